// Round 1
// baseline (1295.471 us; speedup 1.0000x reference)
//
#include <hip/hip_runtime.h>

#define NN 64
#define NI 6
#define NO 2
#define TT 1024
#define BB 1024
#define ALPHA 0.1f
#define NSCALE 0.13416407864998738f  // sqrt(2/ALPHA) * 0.03

// 256 threads = 64 n  x 4 b ; tid = n*4 + b ; grid = 256 blocks (4 batch each)
__global__ __launch_bounds__(256, 1) void latent_circuit_kernel(
    const float* __restrict__ u,      // (6, T, B)
    const float* __restrict__ rn,     // (64, T, B)
    const float* __restrict__ inn,    // (6, T, B)
    const float* __restrict__ Winp,   // (64, 6)
    const float* __restrict__ Wrec,   // (64, 64)
    const float* __restrict__ Wout,   // (2, 64)
    float* __restrict__ states,       // (64, T, B)
    float* __restrict__ outputs)      // (2, T, B)
{
    // XCD-aware swizzle: 256 blocks, 8 XCDs, 32 consecutive logical blocks/XCD
    const int hw = blockIdx.x;
    const int lb = (hw & 7) * 32 + (hw >> 3);
    const int b_base = lb * 4;

    const int tid = threadIdx.x;
    const int n  = tid >> 2;   // 0..63
    const int b  = tid & 3;    // 0..3
    const int gb = b_base + b; // global batch index

    __shared__ __align__(16) float xbuf[2][4][68]; // state double buffer, pad 68
    __shared__ float sbuf[2][4][8];                // staged (u + c*inn) per (b,i)
    __shared__ float part[2][4][4][2];             // [buf][wave][b][o]

    // ---- per-thread weights in registers ----
    float wr[NN];
#pragma unroll
    for (int k = 0; k < NN; ++k) wr[k] = Wrec[n * NN + k];
    float wi[NI];
#pragma unroll
    for (int i = 0; i < NI; ++i) wi[i] = Winp[n * NI + i];
    const float wo0 = Wout[n];
    const float wo1 = Wout[NN + n];

    const int TB = TT * BB;

    // ---- init: x0 = 0, states[:,0,:] = 0, outputs[:,0,:] = 0 ----
    xbuf[0][b][n] = 0.0f;
    states[n * TB + 0 * BB + gb] = 0.0f;
    if (tid < 8) {
        int o  = tid >> 2;
        int bb2 = tid & 3;
        outputs[o * TB + 0 * BB + b_base + bb2] = 0.0f;
    }

    // ---- prefetch registers (distance 2) ----
    float rn_s[2];
    rn_s[0] = rn[n * TB + 0 * BB + gb];  // step 0
    rn_s[1] = rn[n * TB + 1 * BB + gb];  // step 1

    const bool sl = (tid < NI * 4);  // lanes staging input term; i == n here
    float su_s[2] = {0.f, 0.f}, si_s[2] = {0.f, 0.f};
    if (sl) {
        // step 0 synchronous
        float u0 = u[n * TB + 0 * BB + gb];
        float i0 = inn[n * TB + 0 * BB + gb];
        sbuf[0][b][n] = u0 + NSCALE * i0;
        // step 1 -> slot 1, step 2 -> slot 0
        su_s[1] = u[n * TB + 1 * BB + gb];
        si_s[1] = inn[n * TB + 1 * BB + gb];
        su_s[0] = u[n * TB + 2 * BB + gb];
        si_s[0] = inn[n * TB + 2 * BB + gb];
    }
    __syncthreads();

    for (int t = 0; t < TT - 1; ++t) {
        const int c  = t & 1;
        const int nx = c ^ 1;

        // consume prefetched rn for step t; prefetch t+2
        const float rcur = rn_s[c];
        {
            int tp2 = t + 2;
            if (tp2 > TT - 2) tp2 = TT - 2;
            rn_s[c] = rn[n * TB + tp2 * BB + gb];
        }

        // ---- pre = sum_k x[b][k] * Wrec[n][k]  (broadcast LDS reads) ----
        const float4* xrow = (const float4*)(&xbuf[c][b][0]);
        float ax = 0.f, ay = 0.f, az = 0.f, aw = 0.f;
#pragma unroll
        for (int k4 = 0; k4 < 16; ++k4) {
            float4 xv = xrow[k4];
            ax += xv.x * wr[4 * k4 + 0];
            ay += xv.y * wr[4 * k4 + 1];
            az += xv.z * wr[4 * k4 + 2];
            aw += xv.w * wr[4 * k4 + 3];
        }
        float pre = (ax + ay) + (az + aw);
#pragma unroll
        for (int i = 0; i < NI; ++i) pre += sbuf[c][b][i] * wi[i];

        const float xold = xbuf[c][b][n];
        const float act  = pre > 0.f ? pre : 0.f;
        const float xn   = (1.0f - ALPHA) * xold + ALPHA * (act + NSCALE * rcur);

        // ---- write state (global + LDS next buffer) ----
        states[n * TB + (t + 1) * BB + gb] = xn;
        xbuf[nx][b][n] = xn;

        // ---- stage input term for step t+1; prefetch step t+3 ----
        if (sl) {
            sbuf[nx][b][n] = su_s[nx] + NSCALE * si_s[nx];
            int tp3 = t + 3;
            if (tp3 > TT - 2) tp3 = TT - 2;
            su_s[nx] = u[n * TB + tp3 * BB + gb];
            si_s[nx] = inn[n * TB + tp3 * BB + gb];
        }

        // ---- fused output projection: reduce over 16 n-lanes (bits 2..5) ----
        float p0 = wo0 * xn;
        float p1 = wo1 * xn;
        p0 += __shfl_xor(p0, 4);  p1 += __shfl_xor(p1, 4);
        p0 += __shfl_xor(p0, 8);  p1 += __shfl_xor(p1, 8);
        p0 += __shfl_xor(p0, 16); p1 += __shfl_xor(p1, 16);
        p0 += __shfl_xor(p0, 32); p1 += __shfl_xor(p1, 32);
        if ((tid & 63) < 4) {
            int w = tid >> 6;
            part[c][w][b][0] = p0;
            part[c][w][b][1] = p1;
        }

        __syncthreads();

        if (tid < 8) {
            int o   = tid >> 2;
            int bb2 = tid & 3;
            float s = part[c][0][bb2][o] + part[c][1][bb2][o] +
                      part[c][2][bb2][o] + part[c][3][bb2][o];
            outputs[o * TB + (t + 1) * BB + b_base + bb2] = s;
        }
    }
}

extern "C" void kernel_launch(void* const* d_in, const int* in_sizes, int n_in,
                              void* d_out, int out_size, void* d_ws, size_t ws_size,
                              hipStream_t stream) {
    const float* u    = (const float*)d_in[0];
    const float* rn   = (const float*)d_in[1];
    const float* inn  = (const float*)d_in[2];
    const float* Winp = (const float*)d_in[3];
    const float* Wrec = (const float*)d_in[4];
    const float* Wout = (const float*)d_in[5];

    float* states  = (float*)d_out;                          // 64*1024*1024
    float* outputs = (float*)d_out + (size_t)NN * TT * BB;   // 2*1024*1024

    latent_circuit_kernel<<<256, 256, 0, stream>>>(
        u, rn, inn, Winp, Wrec, Wout, states, outputs);
}